// Round 8
// baseline (226.226 us; speedup 1.0000x reference)
//
#include <hip/hip_runtime.h>
#include <hip/hip_fp16.h>
#include <hip/hip_bf16.h>
#include <math.h>

typedef __attribute__((ext_vector_type(8))) short bf16x8;
typedef __attribute__((ext_vector_type(4))) float f32x4;

__device__ __forceinline__ unsigned short f2bf(float x) {
    union { float f; unsigned u; } v; v.f = x;
    unsigned r = v.u + 0x7FFFu + ((v.u >> 16) & 1u);   // RNE
    return (unsigned short)(r >> 16);
}
__device__ __forceinline__ unsigned short f2h(float x) {
    union { __half h; unsigned short u; } v; v.h = __float2half(x); return v.u;
}
__device__ __forceinline__ float h2f(unsigned short u) {
    union { __half h; unsigned short u; } v; v.u = u; return __half2float(v.h);
}
// pack 8 fp32 -> bf16x8 (RNE, HW packed cvt)
__device__ __forceinline__ bf16x8 pack8(const float* p) {
    union { bf16x8 v; __hip_bfloat162 b[4]; } u;
    #pragma unroll
    for (int i = 0; i < 4; ++i)
        u.b[i] = __float22bfloat162_rn(make_float2(p[2 * i], p[2 * i + 1]));
    return u.v;
}

// XCD-aware tile decode (R4-verified).
template<bool M_INNER>
__device__ __forceinline__ void tile_decode(int id, int NT, int MT, int ML,
                                            int& m, int& n, int& zz)
{
    const int xcd = id & 7;
    const int s = id >> 3;
    int mloc;
    if (M_INNER) { mloc = s % ML; n = s / ML; }
    else         { n = s % NT;   mloc = s / NT; }
    const int g = xcd * ML + mloc;
    m = g % MT;
    zz = g / MT;
}

// Async global->LDS staging of a ROWSx64 bf16 tile, 16B DMA, XOR-swizzled:
// LDS slot cc of row R holds global chunk cc ^ (R&7); reads use q ^ (R&7).
template<int ROWS>
__device__ __forceinline__ void stage64(const unsigned short* g, long lda,
                                        unsigned short* lds, int wave, int lane)
{
    const int rr = lane >> 3, cc = lane & 7;
    const int ccg = (cc ^ rr) * 8;
    #pragma unroll
    for (int s = 0; s < ROWS / 32; ++s) {
        const int seg = wave * (ROWS / 32) + s;
        const unsigned short* gp = g + (long)(seg * 8 + rr) * lda + ccg;
        __builtin_amdgcn_global_load_lds(
            (const __attribute__((address_space(1))) void*)gp,
            (__attribute__((address_space(3))) void*)(lds + seg * 512),
            16, 0, 0);
    }
}

// ---------------------------------------------------------------------------
// 4 weights [512][512] fp32 -> transposed bf16, one dispatch.
struct WT4Args {
    const float* src[4];
    unsigned short* dh[4];
};
__global__ __launch_bounds__(256)
void wtrans4(WT4Args a)
{
    __shared__ float T[32][33];
    const int z = blockIdx.z;
    const int Cc = 512, R = 512;
    const float* s = a.src[z];
    const int r0 = blockIdx.y * 32, c0 = blockIdx.x * 32;
    const int t = threadIdx.x;
    {
        const int r = t >> 3, cq = (t & 7) * 4;
        float4 v = *(const float4*)(s + (long)(r0 + r) * Cc + c0 + cq);
        T[r][cq] = v.x; T[r][cq + 1] = v.y; T[r][cq + 2] = v.z; T[r][cq + 3] = v.w;
    }
    __syncthreads();
    {
        const int c = t >> 3, rq = (t & 7) * 4;
        ushort4 h;
        h.x = f2bf(T[rq][c]); h.y = f2bf(T[rq + 1][c]);
        h.z = f2bf(T[rq + 2][c]); h.w = f2bf(T[rq + 3][c]);
        *(ushort4*)(a.dh[z] + (long)(c0 + c) * R + r0 + rq) = h;
    }
}

// ---------------------------------------------------------------------------
// Merged Q/K/V projection, 128x128 tile, BK=64. A: fp32 source, fused cvt,
// VGPR staging into padded LDS (stride 72). B: bf16 weights via swizzled DMA.
struct ProjArgs {
    const float* Af[3];
    const unsigned short* Bh[3];
    const float* bias[3];
    unsigned short* Ch[3];
};
__global__ __launch_bounds__(256)
void proj_gemm(ProjArgs pa)
{
    __shared__ __align__(16) unsigned short smA[128 * 72];   // padded, no xor
    __shared__ __align__(16) unsigned short smB[128 * 64];   // DMA, xor

    int mt, nt, z;
    tile_decode<false>(blockIdx.x, 4, 64, 24, mt, nt, z);

    const float* pAf = pa.Af[z] + (long)(mt * 128) * 512;
    const unsigned short* pBh = pa.Bh[z] + (long)(nt * 128) * 512;
    const float* bias = pa.bias[z];

    const int tid = threadIdx.x;
    const int m0 = mt * 128, n0 = nt * 128;
    const int wave = tid >> 6, lane = tid & 63;
    const int wr = wave >> 1, wc = wave & 1;
    const int quad = lane >> 4, mr = lane & 15;
    const int sw = mr & 7;
    const int tr = tid >> 1, hf = tid & 1;   // A staging: row, 32-float half

    f32x4 acc[4][4] = {};

    for (int k0 = 0; k0 < 512; k0 += 64) {
        // A: fp32 -> bf16 staging
        {
            const float* src = pAf + (long)tr * 512 + k0 + hf * 32;
            #pragma unroll
            for (int jj = 0; jj < 4; ++jj) {
                float4 a = *(const float4*)(src + jj * 8);
                float4 b = *(const float4*)(src + jj * 8 + 4);
                float t[8] = { a.x, a.y, a.z, a.w, b.x, b.y, b.z, b.w };
                *(bf16x8*)&smA[tr * 72 + hf * 32 + jj * 8] = pack8(t);
            }
        }
        stage64<128>(pBh + k0, 512, smB, wave, lane);
        __syncthreads();
        #pragma unroll
        for (int h = 0; h < 2; ++h) {
            const int q2 = (h << 2) | quad;
            bf16x8 af[4], bf[4];
            #pragma unroll
            for (int r = 0; r < 4; ++r)
                af[r] = *(const bf16x8*)&smA[(wr * 64 + r * 16 + mr) * 72 + (q2 << 3)];
            #pragma unroll
            for (int c = 0; c < 4; ++c)
                bf[c] = *(const bf16x8*)&smB[(wc * 64 + c * 16 + mr) * 64 + ((q2 ^ sw) << 3)];
            #pragma unroll
            for (int r = 0; r < 4; ++r)
                #pragma unroll
                for (int c = 0; c < 4; ++c)
                    acc[r][c] = __builtin_amdgcn_mfma_f32_16x16x32_bf16(af[r], bf[c], acc[r][c], 0, 0, 0);
        }
        __syncthreads();
    }

    if (z < 2) {
        unsigned short* Chi = pa.Ch[z];
        #pragma unroll
        for (int r = 0; r < 4; ++r)
            #pragma unroll
            for (int c = 0; c < 4; ++c) {
                const int col = n0 + wc * 64 + c * 16 + mr;
                const float bv = bias[col];
                #pragma unroll
                for (int e = 0; e < 4; ++e) {
                    const int rowg = m0 + wr * 64 + r * 16 + quad * 4 + e;
                    Chi[(long)rowg * 512 + col] = f2bf(acc[r][c][e] + bv);
                }
            }
    } else {
        // transposed: VT[b][col][l]
        unsigned short* VTh = pa.Ch[2];
        #pragma unroll
        for (int r = 0; r < 4; ++r)
            #pragma unroll
            for (int c = 0; c < 4; ++c) {
                const int col = n0 + wc * 64 + c * 16 + mr;
                const float bv = bias[col];
                const int rowg0 = m0 + wr * 64 + r * 16 + quad * 4;
                const int b = rowg0 >> 11, l0 = rowg0 & 2047;
                ushort4 hv;
                hv.x = f2bf(acc[r][c][0] + bv);
                hv.y = f2bf(acc[r][c][1] + bv);
                hv.z = f2bf(acc[r][c][2] + bv);
                hv.w = f2bf(acc[r][c][3] + bv);
                *(ushort4*)(VTh + (long)b * (512 * 2048) + (long)col * 2048 + l0) = hv;
            }
    }
}

// ---------------------------------------------------------------------------
// QK^T: S(fp16) = scale * Q @ K^T, PLUS per-(row, n-tile) softmax partials
// (m_i, l_i) -> stats[b][row][nt]. 128x128 tile, BK=64, swizzled staging.
union QKTSmem {
    unsigned short stage[2][128 * 64];   // 32 KB staging
    unsigned short ep[128 * 132];        // 33.8 KB epilogue transpose
};
__global__ __launch_bounds__(256)
void qkt_gemm(const unsigned short* __restrict__ Qg, const unsigned short* __restrict__ Kg,
              unsigned short* __restrict__ Sg, float2* __restrict__ stats, float alpha)
{
    __shared__ __align__(16) QKTSmem sm;

    int mt, nt, zz;
    tile_decode<true>(blockIdx.x, 16, 16, 8, mt, nt, zz);

    const int tid = threadIdx.x;
    const int m0 = mt * 128, n0 = nt * 128;
    const long LC = 2048L * 512;
    const unsigned short* pA = Qg + (long)zz * LC + (long)m0 * 512;
    const unsigned short* pB = Kg + (long)zz * LC + (long)n0 * 512;

    const int wave = tid >> 6, lane = tid & 63;
    const int wr = wave >> 1, wc = wave & 1;
    const int quad = lane >> 4, mr = lane & 15;
    const int sw = mr & 7;

    f32x4 acc[4][4] = {};

    for (int k0 = 0; k0 < 512; k0 += 64) {
        stage64<128>(pA + k0, 512, sm.stage[0], wave, lane);
        stage64<128>(pB + k0, 512, sm.stage[1], wave, lane);
        __syncthreads();
        #pragma unroll
        for (int h = 0; h < 2; ++h) {
            const int q2 = (h << 2) | quad;
            bf16x8 af[4], bf[4];
            #pragma unroll
            for (int r = 0; r < 4; ++r)
                af[r] = *(const bf16x8*)&sm.stage[0][(wr * 64 + r * 16 + mr) * 64 + ((q2 ^ sw) << 3)];
            #pragma unroll
            for (int c = 0; c < 4; ++c)
                bf[c] = *(const bf16x8*)&sm.stage[1][(wc * 64 + c * 16 + mr) * 64 + ((q2 ^ sw) << 3)];
            #pragma unroll
            for (int r = 0; r < 4; ++r)
                #pragma unroll
                for (int c = 0; c < 4; ++c)
                    acc[r][c] = __builtin_amdgcn_mfma_f32_16x16x32_bf16(af[r], bf[c], acc[r][c], 0, 0, 0);
        }
        __syncthreads();
    }

    // epilogue: acc -> LDS fp16 (transposed) -> coalesced stores + row stats
    #pragma unroll
    for (int r = 0; r < 4; ++r)
        #pragma unroll
        for (int c = 0; c < 4; ++c) {
            const int col = wc * 64 + c * 16 + mr;
            #pragma unroll
            for (int e = 0; e < 4; ++e) {
                const int rowl = wr * 64 + r * 16 + quad * 4 + e;
                sm.ep[rowl * 132 + col] = f2h(acc[r][c][e] * alpha);
            }
        }
    __syncthreads();
    {
        const int R = tid >> 1, hh = tid & 1;
        const unsigned short* src = &sm.ep[R * 132 + hh * 64];
        unsigned short* dst = Sg + (long)zz * (2048L * 2048) + (long)(m0 + R) * 2048 + n0 + hh * 64;
        bf16x8 ch[8];
        #pragma unroll
        for (int j = 0; j < 8; ++j) {
            ch[j] = *(const bf16x8*)(src + j * 8);
            *(bf16x8*)(dst + j * 8) = ch[j];
        }
        // partial softmax stats over this 128-col tile (pair tid, tid^1 = same row)
        float mloc = -1e30f;
        #pragma unroll
        for (int j = 0; j < 8; ++j)
            #pragma unroll
            for (int i = 0; i < 8; ++i)
                mloc = fmaxf(mloc, h2f((unsigned short)ch[j][i]));
        const float m2 = fmaxf(mloc, __shfl_xor(mloc, 1));
        float sl = 0.f;
        #pragma unroll
        for (int j = 0; j < 8; ++j)
            #pragma unroll
            for (int i = 0; i < 8; ++i)
                sl += __expf(h2f((unsigned short)ch[j][i]) - m2);
        sl += __shfl_xor(sl, 1);
        if (hh == 0)
            stats[((long)zz * 2048 + m0 + R) * 16 + nt] = make_float2(m2, sl);
    }
}

// ---------------------------------------------------------------------------
// PV with fused softmax finalization: O(bf16) = softmax(S) @ V.
// A-staging reads S fp16 and applies exp(s-m)/l on the fly (padded LDS);
// B = VT via swizzled DMA. 64x128 tile, BK=64, K=2048.
__global__ __launch_bounds__(256)
void pv_gemm(const unsigned short* __restrict__ Sg, const unsigned short* __restrict__ VTg,
             const float2* __restrict__ stats, unsigned short* __restrict__ Og)
{
    __shared__ __align__(16) unsigned short smA[64 * 72];    // padded, no xor
    __shared__ __align__(16) unsigned short smB[128 * 64];   // DMA, xor

    int mt, nt, zz;
    tile_decode<false>(blockIdx.x, 4, 32, 16, mt, nt, zz);

    const int tid = threadIdx.x;
    const int m0 = mt * 64, n0 = nt * 128;
    const long LL = 2048L * 2048, LC = 2048L * 512;
    const unsigned short* pS = Sg + (long)zz * LL + (long)m0 * 2048;
    const unsigned short* pB = VTg + (long)zz * LC + (long)n0 * 2048;

    const int wave = tid >> 6, lane = tid & 63;
    const int quad = lane >> 4, mr = lane & 15;
    const int sw = mr & 7;
    const int tr = tid >> 2, qt = tid & 3;   // A staging: row 0..63, 16-col quarter

    // finalize row stats for staging row tr
    float m_row, inv_row;
    {
        const float2* st = stats + ((long)zz * 2048 + m0 + tr) * 16;
        float2 s[16];
        float m = -1e30f;
        #pragma unroll
        for (int i = 0; i < 16; ++i) { s[i] = st[i]; m = fmaxf(m, s[i].x); }
        float l = 0.f;
        #pragma unroll
        for (int i = 0; i < 16; ++i) l += s[i].y * __expf(s[i].x - m);
        m_row = m;
        inv_row = 1.0f / l;
    }

    f32x4 acc[4][2] = {};

    for (int k0 = 0; k0 < 2048; k0 += 64) {
        // A: fp16 S -> p = exp(s-m)/l -> bf16 staging
        {
            const unsigned short* srow = pS + (long)tr * 2048 + k0 + qt * 16;
            #pragma unroll
            for (int c2 = 0; c2 < 2; ++c2) {
                bf16x8 hv = *(const bf16x8*)(srow + c2 * 8);
                float t[8];
                #pragma unroll
                for (int i = 0; i < 8; ++i)
                    t[i] = __expf(h2f((unsigned short)hv[i]) - m_row) * inv_row;
                *(bf16x8*)&smA[tr * 72 + qt * 16 + c2 * 8] = pack8(t);
            }
        }
        stage64<128>(pB + k0, 2048, smB, wave, lane);
        __syncthreads();
        #pragma unroll
        for (int h = 0; h < 2; ++h) {
            const int q2 = (h << 2) | quad;
            bf16x8 af[4], bf[2];
            #pragma unroll
            for (int r = 0; r < 4; ++r)
                af[r] = *(const bf16x8*)&smA[(r * 16 + mr) * 72 + (q2 << 3)];
            #pragma unroll
            for (int c = 0; c < 2; ++c)
                bf[c] = *(const bf16x8*)&smB[(wave * 32 + c * 16 + mr) * 64 + ((q2 ^ sw) << 3)];
            #pragma unroll
            for (int r = 0; r < 4; ++r)
                #pragma unroll
                for (int c = 0; c < 2; ++c)
                    acc[r][c] = __builtin_amdgcn_mfma_f32_16x16x32_bf16(af[r], bf[c], acc[r][c], 0, 0, 0);
        }
        __syncthreads();
    }

    #pragma unroll
    for (int r = 0; r < 4; ++r)
        #pragma unroll
        for (int c = 0; c < 2; ++c) {
            const int col = n0 + wave * 32 + c * 16 + mr;
            #pragma unroll
            for (int e = 0; e < 4; ++e) {
                const int rowg = m0 + r * 16 + quad * 4 + e;
                Og[(long)zz * LC + (long)rowg * 512 + col] = f2bf(acc[r][c][e]);
            }
        }
}

// ---------------------------------------------------------------------------
// Final projection: out(fp32) = O @ Wo^T + bo. 64x128 tile, BK=64, all-DMA.
__global__ __launch_bounds__(256)
void oproj_gemm(const unsigned short* __restrict__ Ag, const unsigned short* __restrict__ Bg,
                float* __restrict__ Cf, const float* __restrict__ bias)
{
    __shared__ __align__(16) unsigned short smA[64 * 64];
    __shared__ __align__(16) unsigned short smB[128 * 64];

    int mt, nt, zz;
    tile_decode<false>(blockIdx.x, 4, 128, 16, mt, nt, zz);
    (void)zz;

    const int tid = threadIdx.x;
    const int m0 = mt * 64, n0 = nt * 128;
    const unsigned short* pA = Ag + (long)m0 * 512;
    const unsigned short* pB = Bg + (long)n0 * 512;

    const int wave = tid >> 6, lane = tid & 63;
    const int quad = lane >> 4, mr = lane & 15;
    const int sw = mr & 7;

    f32x4 acc[4][2] = {};

    for (int k0 = 0; k0 < 512; k0 += 64) {
        stage64<64>(pA + k0, 512, smA, wave, lane);
        stage64<128>(pB + k0, 512, smB, wave, lane);
        __syncthreads();
        #pragma unroll
        for (int h = 0; h < 2; ++h) {
            const int q2 = (h << 2) | quad;
            bf16x8 af[4], bf[2];
            #pragma unroll
            for (int r = 0; r < 4; ++r)
                af[r] = *(const bf16x8*)&smA[(r * 16 + mr) * 64 + ((q2 ^ sw) << 3)];
            #pragma unroll
            for (int c = 0; c < 2; ++c)
                bf[c] = *(const bf16x8*)&smB[(wave * 32 + c * 16 + mr) * 64 + ((q2 ^ sw) << 3)];
            #pragma unroll
            for (int r = 0; r < 4; ++r)
                #pragma unroll
                for (int c = 0; c < 2; ++c)
                    acc[r][c] = __builtin_amdgcn_mfma_f32_16x16x32_bf16(af[r], bf[c], acc[r][c], 0, 0, 0);
        }
        __syncthreads();
    }

    #pragma unroll
    for (int r = 0; r < 4; ++r)
        #pragma unroll
        for (int c = 0; c < 2; ++c) {
            const int col = n0 + wave * 32 + c * 16 + mr;
            const float bv = bias[col];
            #pragma unroll
            for (int e = 0; e < 4; ++e) {
                const int rowg = m0 + r * 16 + quad * 4 + e;
                Cf[(long)rowg * 512 + col] = acc[r][c][e] + bv;
            }
        }
}

// ---------------------------------------------------------------------------
extern "C" void kernel_launch(void* const* d_in, const int* in_sizes, int n_in,
                              void* d_out, int out_size, void* d_ws, size_t ws_size,
                              hipStream_t stream) {
    const float* query = (const float*)d_in[0];
    const float* key   = (const float*)d_in[1];
    const float* value = (const float*)d_in[2];
    const float* Wq    = (const float*)d_in[3];
    const float* bq    = (const float*)d_in[4];
    const float* Wk    = (const float*)d_in[5];
    const float* bk    = (const float*)d_in[6];
    const float* Wv    = (const float*)d_in[7];
    const float* bv    = (const float*)d_in[8];
    const float* Wo    = (const float*)d_in[9];
    const float* bo    = (const float*)d_in[10];
    float* out = (float*)d_out;

    const int B = 4, L = 2048, C = 512;
    char* ws = (char*)d_ws;

    // ---- workspace map (bytes), total ~70.2 MB ----------------------------
    // [0, 2.10M):       WT_h x4
    // [2.10M, 10.5M):   Q_h        [10.5M, 18.9M):  K_h
    // [18.9M, 27.3M):   VT_h       [27.3M, 60.8M):  S fp16 (33.5 MB)
    // [60.8M, 61.8M):   stats float2[4][2048][16] (1 MB)
    // [61.8M, 70.2M):   O_h
    unsigned short* WqT_h = (unsigned short*)(ws);
    unsigned short* WkT_h = (unsigned short*)(ws + 524288);
    unsigned short* WvT_h = (unsigned short*)(ws + 1048576);
    unsigned short* WoT_h = (unsigned short*)(ws + 1572864);
    unsigned short* Q_h   = (unsigned short*)(ws + 2097152);
    unsigned short* K_h   = (unsigned short*)(ws + 10485760);
    unsigned short* VT_h  = (unsigned short*)(ws + 18874368);
    unsigned short* S     = (unsigned short*)(ws + 27262976);
    float2*         stats = (float2*)(ws + 60817408);
    unsigned short* O_h   = (unsigned short*)(ws + 61865984);

    const dim3 blk(256);
    const float scale = 1.0f / sqrtf((float)C);

    // 1) weight transposes -> bf16
    WT4Args wt;
    wt.src[0] = Wq; wt.src[1] = Wk; wt.src[2] = Wv; wt.src[3] = Wo;
    wt.dh[0] = WqT_h; wt.dh[1] = WkT_h; wt.dh[2] = WvT_h; wt.dh[3] = WoT_h;
    wtrans4<<<dim3(16, 16, 4), blk, 0, stream>>>(wt);

    // 2) merged projections, fp32 inputs fused-converted (768 blocks)
    ProjArgs pa;
    pa.Af[0] = query; pa.Bh[0] = WqT_h; pa.bias[0] = bq; pa.Ch[0] = Q_h;
    pa.Af[1] = key;   pa.Bh[1] = WkT_h; pa.bias[1] = bk; pa.Ch[1] = K_h;
    pa.Af[2] = value; pa.Bh[2] = WvT_h; pa.bias[2] = bv; pa.Ch[2] = VT_h;
    proj_gemm<<<dim3(768), blk, 0, stream>>>(pa);

    // 3) S = scale * Q @ K^T -> fp16 + per-tile softmax partials (1024 blocks)
    qkt_gemm<<<dim3(1024), blk, 0, stream>>>(Q_h, K_h, S, stats, scale);

    // 4) O = softmax(S) @ V -> bf16, softmax fused into A-staging (512 blocks)
    pv_gemm<<<dim3(512), blk, 0, stream>>>(S, VT_h, stats, O_h);

    // 5) out = O @ Wo^T + bo, fp32 (512 blocks)
    oproj_gemm<<<dim3(512), blk, 0, stream>>>(O_h, WoT_h, out, bo);
}

// Round 9
// 224.703 us; speedup vs baseline: 1.0068x; 1.0068x over previous
//
#include <hip/hip_runtime.h>
#include <hip/hip_fp16.h>
#include <hip/hip_bf16.h>
#include <math.h>

typedef __attribute__((ext_vector_type(8))) short bf16x8;
typedef __attribute__((ext_vector_type(4))) float f32x4;

__device__ __forceinline__ unsigned short f2bf(float x) {
    union { float f; unsigned u; } v; v.f = x;
    unsigned r = v.u + 0x7FFFu + ((v.u >> 16) & 1u);   // RNE
    return (unsigned short)(r >> 16);
}
__device__ __forceinline__ unsigned short f2h(float x) {
    union { __half h; unsigned short u; } v; v.h = __float2half(x); return v.u;
}
__device__ __forceinline__ float h2f(unsigned short u) {
    union { __half h; unsigned short u; } v; v.u = u; return __half2float(v.h);
}
// pack 8 fp32 -> bf16x8 (RNE, HW packed cvt)
__device__ __forceinline__ bf16x8 pack8(const float* p) {
    union { bf16x8 v; __hip_bfloat162 b[4]; } u;
    #pragma unroll
    for (int i = 0; i < 4; ++i)
        u.b[i] = __float22bfloat162_rn(make_float2(p[2 * i], p[2 * i + 1]));
    return u.v;
}

// XCD-aware tile decode (R4-verified).
template<bool M_INNER>
__device__ __forceinline__ void tile_decode(int id, int NT, int MT, int ML,
                                            int& m, int& n, int& zz)
{
    const int xcd = id & 7;
    const int s = id >> 3;
    int mloc;
    if (M_INNER) { mloc = s % ML; n = s / ML; }
    else         { n = s % NT;   mloc = s / NT; }
    const int g = xcd * ML + mloc;
    m = g % MT;
    zz = g / MT;
}

// Async global->LDS staging of a ROWSx64 bf16 tile, 16B DMA, XOR-swizzled:
// LDS slot cc of row R holds global chunk cc ^ (R&7); reads use q ^ (R&7).
template<int ROWS>
__device__ __forceinline__ void stage64(const unsigned short* g, long lda,
                                        unsigned short* lds, int wave, int lane)
{
    const int rr = lane >> 3, cc = lane & 7;
    const int ccg = (cc ^ rr) * 8;
    #pragma unroll
    for (int s = 0; s < ROWS / 32; ++s) {
        const int seg = wave * (ROWS / 32) + s;
        const unsigned short* gp = g + (long)(seg * 8 + rr) * lda + ccg;
        __builtin_amdgcn_global_load_lds(
            (const __attribute__((address_space(1))) void*)gp,
            (__attribute__((address_space(3))) void*)(lds + seg * 512),
            16, 0, 0);
    }
}

// ---------------------------------------------------------------------------
// 4 weights [512][512] fp32 -> transposed bf16, one dispatch.
struct WT4Args {
    const float* src[4];
    unsigned short* dh[4];
};
__global__ __launch_bounds__(256)
void wtrans4(WT4Args a)
{
    __shared__ float T[32][33];
    const int z = blockIdx.z;
    const int Cc = 512, R = 512;
    const float* s = a.src[z];
    const int r0 = blockIdx.y * 32, c0 = blockIdx.x * 32;
    const int t = threadIdx.x;
    {
        const int r = t >> 3, cq = (t & 7) * 4;
        float4 v = *(const float4*)(s + (long)(r0 + r) * Cc + c0 + cq);
        T[r][cq] = v.x; T[r][cq + 1] = v.y; T[r][cq + 2] = v.z; T[r][cq + 3] = v.w;
    }
    __syncthreads();
    {
        const int c = t >> 3, rq = (t & 7) * 4;
        ushort4 h;
        h.x = f2bf(T[rq][c]); h.y = f2bf(T[rq + 1][c]);
        h.z = f2bf(T[rq + 2][c]); h.w = f2bf(T[rq + 3][c]);
        *(ushort4*)(a.dh[z] + (long)(c0 + c) * R + r0 + rq) = h;
    }
}

// ---------------------------------------------------------------------------
// Merged Q/K/V projection, 128x128 tile, BK=64. A: fp32 source, fused cvt,
// VGPR staging SOFTWARE-PIPELINED (prefetch k+1 during compute of k), XOR-
// swizzled LDS. B: bf16 weights via swizzled DMA.
struct ProjArgs {
    const float* Af[3];
    const unsigned short* Bh[3];
    const float* bias[3];
    unsigned short* Ch[3];
};
__global__ __launch_bounds__(256)
void proj_gemm(ProjArgs pa)
{
    __shared__ __align__(16) unsigned short smA[128 * 64];
    __shared__ __align__(16) unsigned short smB[128 * 64];

    int mt, nt, z;
    tile_decode<false>(blockIdx.x, 4, 64, 24, mt, nt, z);

    const float* pAf = pa.Af[z] + (long)(mt * 128) * 512;
    const unsigned short* pBh = pa.Bh[z] + (long)(nt * 128) * 512;
    const float* bias = pa.bias[z];

    const int tid = threadIdx.x;
    const int m0 = mt * 128, n0 = nt * 128;
    const int wave = tid >> 6, lane = tid & 63;
    const int wr = wave >> 1, wc = wave & 1;
    const int quad = lane >> 4, mr = lane & 15;
    const int sw = mr & 7;
    const int tr = tid >> 1, hf = tid & 1;   // A staging: row, 32-float half
    const int swA = tr & 7;

    f32x4 acc[4][4] = {};

    // prefetch k0=0 A block (32 fp32/thread)
    float4 pre[8];
    {
        const float* s0 = pAf + (long)tr * 512 + hf * 32;
        #pragma unroll
        for (int jj = 0; jj < 8; ++jj) pre[jj] = *(const float4*)(s0 + jj * 4);
    }

    for (int k0 = 0; k0 < 512; k0 += 64) {
        // write prefetched A (cvt fp32->bf16) into xor-swizzled LDS
        #pragma unroll
        for (int jj = 0; jj < 4; ++jj) {
            float t[8] = { pre[2 * jj].x, pre[2 * jj].y, pre[2 * jj].z, pre[2 * jj].w,
                           pre[2 * jj + 1].x, pre[2 * jj + 1].y, pre[2 * jj + 1].z, pre[2 * jj + 1].w };
            const int cc = hf * 4 + jj;
            *(bf16x8*)&smA[tr * 64 + ((cc ^ swA) << 3)] = pack8(t);
        }
        stage64<128>(pBh + k0, 512, smB, wave, lane);
        __syncthreads();

        // issue next iter's A loads NOW; their wait lands after the MFMAs
        if (k0 + 64 < 512) {
            const float* s2 = pAf + (long)tr * 512 + (k0 + 64) + hf * 32;
            #pragma unroll
            for (int jj = 0; jj < 8; ++jj) pre[jj] = *(const float4*)(s2 + jj * 4);
        }

        #pragma unroll
        for (int h = 0; h < 2; ++h) {
            const int q2 = (h << 2) | quad;
            bf16x8 af[4], bf[4];
            #pragma unroll
            for (int r = 0; r < 4; ++r)
                af[r] = *(const bf16x8*)&smA[(wr * 64 + r * 16 + mr) * 64 + ((q2 ^ sw) << 3)];
            #pragma unroll
            for (int c = 0; c < 4; ++c)
                bf[c] = *(const bf16x8*)&smB[(wc * 64 + c * 16 + mr) * 64 + ((q2 ^ sw) << 3)];
            #pragma unroll
            for (int r = 0; r < 4; ++r)
                #pragma unroll
                for (int c = 0; c < 4; ++c)
                    acc[r][c] = __builtin_amdgcn_mfma_f32_16x16x32_bf16(af[r], bf[c], acc[r][c], 0, 0, 0);
        }
        __syncthreads();
    }

    if (z < 2) {
        unsigned short* Chi = pa.Ch[z];
        #pragma unroll
        for (int r = 0; r < 4; ++r)
            #pragma unroll
            for (int c = 0; c < 4; ++c) {
                const int col = n0 + wc * 64 + c * 16 + mr;
                const float bv = bias[col];
                #pragma unroll
                for (int e = 0; e < 4; ++e) {
                    const int rowg = m0 + wr * 64 + r * 16 + quad * 4 + e;
                    Chi[(long)rowg * 512 + col] = f2bf(acc[r][c][e] + bv);
                }
            }
    } else {
        // transposed: VT[b][col][l]
        unsigned short* VTh = pa.Ch[2];
        #pragma unroll
        for (int r = 0; r < 4; ++r)
            #pragma unroll
            for (int c = 0; c < 4; ++c) {
                const int col = n0 + wc * 64 + c * 16 + mr;
                const float bv = bias[col];
                const int rowg0 = m0 + wr * 64 + r * 16 + quad * 4;
                const int b = rowg0 >> 11, l0 = rowg0 & 2047;
                ushort4 hv;
                hv.x = f2bf(acc[r][c][0] + bv);
                hv.y = f2bf(acc[r][c][1] + bv);
                hv.z = f2bf(acc[r][c][2] + bv);
                hv.w = f2bf(acc[r][c][3] + bv);
                *(ushort4*)(VTh + (long)b * (512 * 2048) + (long)col * 2048 + l0) = hv;
            }
    }
}

// ---------------------------------------------------------------------------
// QK^T: S(fp16) = scale * Q @ K^T, PLUS per-(row, n-tile) softmax partials
// (m_i, l_i) -> stats[b][row][nt]. 128x128 tile, BK=64, swizzled staging.
union QKTSmem {
    unsigned short stage[2][128 * 64];   // 32 KB staging
    unsigned short ep[128 * 132];        // 33.8 KB epilogue transpose
};
__global__ __launch_bounds__(256)
void qkt_gemm(const unsigned short* __restrict__ Qg, const unsigned short* __restrict__ Kg,
              unsigned short* __restrict__ Sg, float2* __restrict__ stats, float alpha)
{
    __shared__ __align__(16) QKTSmem sm;

    int mt, nt, zz;
    tile_decode<true>(blockIdx.x, 16, 16, 8, mt, nt, zz);

    const int tid = threadIdx.x;
    const int m0 = mt * 128, n0 = nt * 128;
    const long LC = 2048L * 512;
    const unsigned short* pA = Qg + (long)zz * LC + (long)m0 * 512;
    const unsigned short* pB = Kg + (long)zz * LC + (long)n0 * 512;

    const int wave = tid >> 6, lane = tid & 63;
    const int wr = wave >> 1, wc = wave & 1;
    const int quad = lane >> 4, mr = lane & 15;
    const int sw = mr & 7;

    f32x4 acc[4][4] = {};

    for (int k0 = 0; k0 < 512; k0 += 64) {
        stage64<128>(pA + k0, 512, sm.stage[0], wave, lane);
        stage64<128>(pB + k0, 512, sm.stage[1], wave, lane);
        __syncthreads();
        #pragma unroll
        for (int h = 0; h < 2; ++h) {
            const int q2 = (h << 2) | quad;
            bf16x8 af[4], bf[4];
            #pragma unroll
            for (int r = 0; r < 4; ++r)
                af[r] = *(const bf16x8*)&sm.stage[0][(wr * 64 + r * 16 + mr) * 64 + ((q2 ^ sw) << 3)];
            #pragma unroll
            for (int c = 0; c < 4; ++c)
                bf[c] = *(const bf16x8*)&sm.stage[1][(wc * 64 + c * 16 + mr) * 64 + ((q2 ^ sw) << 3)];
            #pragma unroll
            for (int r = 0; r < 4; ++r)
                #pragma unroll
                for (int c = 0; c < 4; ++c)
                    acc[r][c] = __builtin_amdgcn_mfma_f32_16x16x32_bf16(af[r], bf[c], acc[r][c], 0, 0, 0);
        }
        __syncthreads();
    }

    // epilogue: acc -> LDS fp16 (transposed) -> coalesced stores + row stats
    #pragma unroll
    for (int r = 0; r < 4; ++r)
        #pragma unroll
        for (int c = 0; c < 4; ++c) {
            const int col = wc * 64 + c * 16 + mr;
            #pragma unroll
            for (int e = 0; e < 4; ++e) {
                const int rowl = wr * 64 + r * 16 + quad * 4 + e;
                sm.ep[rowl * 132 + col] = f2h(acc[r][c][e] * alpha);
            }
        }
    __syncthreads();
    {
        const int R = tid >> 1, hh = tid & 1;
        const unsigned short* src = &sm.ep[R * 132 + hh * 64];
        unsigned short* dst = Sg + (long)zz * (2048L * 2048) + (long)(m0 + R) * 2048 + n0 + hh * 64;
        bf16x8 ch[8];
        #pragma unroll
        for (int j = 0; j < 8; ++j) {
            ch[j] = *(const bf16x8*)(src + j * 8);
            *(bf16x8*)(dst + j * 8) = ch[j];
        }
        // partial softmax stats over this 128-col tile (pair tid, tid^1 = same row)
        float mloc = -1e30f;
        #pragma unroll
        for (int j = 0; j < 8; ++j)
            #pragma unroll
            for (int i = 0; i < 8; ++i)
                mloc = fmaxf(mloc, h2f((unsigned short)ch[j][i]));
        const float m2 = fmaxf(mloc, __shfl_xor(mloc, 1));
        float sl = 0.f;
        #pragma unroll
        for (int j = 0; j < 8; ++j)
            #pragma unroll
            for (int i = 0; i < 8; ++i)
                sl += __expf(h2f((unsigned short)ch[j][i]) - m2);
        sl += __shfl_xor(sl, 1);
        if (hh == 0)
            stats[((long)zz * 2048 + m0 + R) * 16 + nt] = make_float2(m2, sl);
    }
}

// ---------------------------------------------------------------------------
// PV with fused softmax finalization: O(bf16) = softmax(S) @ V.
// A-staging reads S fp16 (PIPELINED prefetch) and applies exp(s-m)/l on the
// fly into xor-swizzled LDS; B = VT via swizzled DMA. 64x128 tile, BK=64.
__global__ __launch_bounds__(256)
void pv_gemm(const unsigned short* __restrict__ Sg, const unsigned short* __restrict__ VTg,
             const float2* __restrict__ stats, unsigned short* __restrict__ Og)
{
    __shared__ __align__(16) unsigned short smA[64 * 64];
    __shared__ __align__(16) unsigned short smB[128 * 64];

    int mt, nt, zz;
    tile_decode<false>(blockIdx.x, 4, 32, 16, mt, nt, zz);

    const int tid = threadIdx.x;
    const int m0 = mt * 64, n0 = nt * 128;
    const long LL = 2048L * 2048, LC = 2048L * 512;
    const unsigned short* pS = Sg + (long)zz * LL + (long)m0 * 2048;
    const unsigned short* pB = VTg + (long)zz * LC + (long)n0 * 2048;

    const int wave = tid >> 6, lane = tid & 63;
    const int quad = lane >> 4, mr = lane & 15;
    const int sw = mr & 7;
    const int tr = tid >> 2, qt = tid & 3;   // A staging: row 0..63, 16-col quarter
    const int swA = tr & 7;

    // finalize row stats for staging row tr
    float m_row, inv_row;
    {
        const float2* st = stats + ((long)zz * 2048 + m0 + tr) * 16;
        float2 s[16];
        float m = -1e30f;
        #pragma unroll
        for (int i = 0; i < 16; ++i) { s[i] = st[i]; m = fmaxf(m, s[i].x); }
        float l = 0.f;
        #pragma unroll
        for (int i = 0; i < 16; ++i) l += s[i].y * __expf(s[i].x - m);
        m_row = m;
        inv_row = 1.0f / l;
    }

    f32x4 acc[4][2] = {};

    bf16x8 pre[2];
    {
        const unsigned short* s0 = pS + (long)tr * 2048 + qt * 16;
        pre[0] = *(const bf16x8*)(s0);
        pre[1] = *(const bf16x8*)(s0 + 8);
    }

    for (int k0 = 0; k0 < 2048; k0 += 64) {
        // exp(s-m)/l on prefetched fp16 -> bf16 -> xor-swizzled LDS
        #pragma unroll
        for (int c2 = 0; c2 < 2; ++c2) {
            float t[8];
            #pragma unroll
            for (int i = 0; i < 8; ++i)
                t[i] = __expf(h2f((unsigned short)pre[c2][i]) - m_row) * inv_row;
            const int cc = qt * 2 + c2;
            *(bf16x8*)&smA[tr * 64 + ((cc ^ swA) << 3)] = pack8(t);
        }
        stage64<128>(pB + k0, 2048, smB, wave, lane);
        __syncthreads();

        // issue next iter's S loads; wait lands after the MFMAs
        if (k0 + 64 < 2048) {
            const unsigned short* s2 = pS + (long)tr * 2048 + (k0 + 64) + qt * 16;
            pre[0] = *(const bf16x8*)(s2);
            pre[1] = *(const bf16x8*)(s2 + 8);
        }

        #pragma unroll
        for (int h = 0; h < 2; ++h) {
            const int q2 = (h << 2) | quad;
            bf16x8 af[4], bf[2];
            #pragma unroll
            for (int r = 0; r < 4; ++r)
                af[r] = *(const bf16x8*)&smA[(r * 16 + mr) * 64 + ((q2 ^ sw) << 3)];
            #pragma unroll
            for (int c = 0; c < 2; ++c)
                bf[c] = *(const bf16x8*)&smB[(wave * 32 + c * 16 + mr) * 64 + ((q2 ^ sw) << 3)];
            #pragma unroll
            for (int r = 0; r < 4; ++r)
                #pragma unroll
                for (int c = 0; c < 2; ++c)
                    acc[r][c] = __builtin_amdgcn_mfma_f32_16x16x32_bf16(af[r], bf[c], acc[r][c], 0, 0, 0);
        }
        __syncthreads();
    }

    #pragma unroll
    for (int r = 0; r < 4; ++r)
        #pragma unroll
        for (int c = 0; c < 2; ++c) {
            const int col = n0 + wave * 32 + c * 16 + mr;
            #pragma unroll
            for (int e = 0; e < 4; ++e) {
                const int rowg = m0 + r * 16 + quad * 4 + e;
                Og[(long)zz * LC + (long)rowg * 512 + col] = f2bf(acc[r][c][e]);
            }
        }
}

// ---------------------------------------------------------------------------
// Final projection: out(fp32) = O @ Wo^T + bo. 64x128 tile, BK=64, all-DMA.
__global__ __launch_bounds__(256)
void oproj_gemm(const unsigned short* __restrict__ Ag, const unsigned short* __restrict__ Bg,
                float* __restrict__ Cf, const float* __restrict__ bias)
{
    __shared__ __align__(16) unsigned short smA[64 * 64];
    __shared__ __align__(16) unsigned short smB[128 * 64];

    int mt, nt, zz;
    tile_decode<false>(blockIdx.x, 4, 128, 16, mt, nt, zz);
    (void)zz;

    const int tid = threadIdx.x;
    const int m0 = mt * 64, n0 = nt * 128;
    const unsigned short* pA = Ag + (long)m0 * 512;
    const unsigned short* pB = Bg + (long)n0 * 512;

    const int wave = tid >> 6, lane = tid & 63;
    const int quad = lane >> 4, mr = lane & 15;
    const int sw = mr & 7;

    f32x4 acc[4][2] = {};

    for (int k0 = 0; k0 < 512; k0 += 64) {
        stage64<64>(pA + k0, 512, smA, wave, lane);
        stage64<128>(pB + k0, 512, smB, wave, lane);
        __syncthreads();
        #pragma unroll
        for (int h = 0; h < 2; ++h) {
            const int q2 = (h << 2) | quad;
            bf16x8 af[4], bf[2];
            #pragma unroll
            for (int r = 0; r < 4; ++r)
                af[r] = *(const bf16x8*)&smA[(r * 16 + mr) * 64 + ((q2 ^ sw) << 3)];
            #pragma unroll
            for (int c = 0; c < 2; ++c)
                bf[c] = *(const bf16x8*)&smB[(wave * 32 + c * 16 + mr) * 64 + ((q2 ^ sw) << 3)];
            #pragma unroll
            for (int r = 0; r < 4; ++r)
                #pragma unroll
                for (int c = 0; c < 2; ++c)
                    acc[r][c] = __builtin_amdgcn_mfma_f32_16x16x32_bf16(af[r], bf[c], acc[r][c], 0, 0, 0);
        }
        __syncthreads();
    }

    #pragma unroll
    for (int r = 0; r < 4; ++r)
        #pragma unroll
        for (int c = 0; c < 2; ++c) {
            const int col = n0 + wave * 32 + c * 16 + mr;
            const float bv = bias[col];
            #pragma unroll
            for (int e = 0; e < 4; ++e) {
                const int rowg = m0 + r * 16 + quad * 4 + e;
                Cf[(long)rowg * 512 + col] = acc[r][c][e] + bv;
            }
        }
}

// ---------------------------------------------------------------------------
extern "C" void kernel_launch(void* const* d_in, const int* in_sizes, int n_in,
                              void* d_out, int out_size, void* d_ws, size_t ws_size,
                              hipStream_t stream) {
    const float* query = (const float*)d_in[0];
    const float* key   = (const float*)d_in[1];
    const float* value = (const float*)d_in[2];
    const float* Wq    = (const float*)d_in[3];
    const float* bq    = (const float*)d_in[4];
    const float* Wk    = (const float*)d_in[5];
    const float* bk    = (const float*)d_in[6];
    const float* Wv    = (const float*)d_in[7];
    const float* bv    = (const float*)d_in[8];
    const float* Wo    = (const float*)d_in[9];
    const float* bo    = (const float*)d_in[10];
    float* out = (float*)d_out;

    const int B = 4, L = 2048, C = 512;
    char* ws = (char*)d_ws;

    // ---- workspace map (bytes), total ~70.2 MB ----------------------------
    unsigned short* WqT_h = (unsigned short*)(ws);
    unsigned short* WkT_h = (unsigned short*)(ws + 524288);
    unsigned short* WvT_h = (unsigned short*)(ws + 1048576);
    unsigned short* WoT_h = (unsigned short*)(ws + 1572864);
    unsigned short* Q_h   = (unsigned short*)(ws + 2097152);
    unsigned short* K_h   = (unsigned short*)(ws + 10485760);
    unsigned short* VT_h  = (unsigned short*)(ws + 18874368);
    unsigned short* S     = (unsigned short*)(ws + 27262976);
    float2*         stats = (float2*)(ws + 60817408);
    unsigned short* O_h   = (unsigned short*)(ws + 61865984);

    const dim3 blk(256);
    const float scale = 1.0f / sqrtf((float)C);

    // 1) weight transposes -> bf16
    WT4Args wt;
    wt.src[0] = Wq; wt.src[1] = Wk; wt.src[2] = Wv; wt.src[3] = Wo;
    wt.dh[0] = WqT_h; wt.dh[1] = WkT_h; wt.dh[2] = WvT_h; wt.dh[3] = WoT_h;
    wtrans4<<<dim3(16, 16, 4), blk, 0, stream>>>(wt);

    // 2) merged projections, fp32 inputs fused-converted, pipelined (768 blocks)
    ProjArgs pa;
    pa.Af[0] = query; pa.Bh[0] = WqT_h; pa.bias[0] = bq; pa.Ch[0] = Q_h;
    pa.Af[1] = key;   pa.Bh[1] = WkT_h; pa.bias[1] = bk; pa.Ch[1] = K_h;
    pa.Af[2] = value; pa.Bh[2] = WvT_h; pa.bias[2] = bv; pa.Ch[2] = VT_h;
    proj_gemm<<<dim3(768), blk, 0, stream>>>(pa);

    // 3) S = scale * Q @ K^T -> fp16 + per-tile softmax partials (1024 blocks)
    qkt_gemm<<<dim3(1024), blk, 0, stream>>>(Q_h, K_h, S, stats, scale);

    // 4) O = softmax(S) @ V -> bf16, softmax fused + pipelined (512 blocks)
    pv_gemm<<<dim3(512), blk, 0, stream>>>(S, VT_h, stats, O_h);

    // 5) out = O @ Wo^T + bo, fp32 (512 blocks)
    oproj_gemm<<<dim3(512), blk, 0, stream>>>(O_h, WoT_h, out, bo);
}